// Round 6
// baseline (337.474 us; speedup 1.0000x reference)
//
#include <hip/hip_runtime.h>
#include <math.h>

#define BB 128
#define TT 2048
#define OO 128
#define EE 512
#define LL 34
#define XDIM 640       // O+E
#define CHUNKS 16
#define CHUNK_LEN 128  // TT / CHUNKS

__device__ __forceinline__ float sigmoidf_(float x) { return 1.0f / (1.0f + __expf(-x)); }

// ---------------- K1: LSTM cell, fused GEMM + activation.
__global__ __launch_bounds__(256) void lstm_kernel(
    const float* __restrict__ y1, const float* __restrict__ c1,
    const float* __restrict__ sh1, const float* __restrict__ sc1,
    const float* __restrict__ Wih, const float* __restrict__ bih,
    const float* __restrict__ Whh, const float* __restrict__ bhh,
    float* __restrict__ out_sh, float* __restrict__ out_sc)
{
    __shared__ float xs[4][768];          // per batch row: [y1(512)|c1(128)|sh1(128)]
    __shared__ float gbuf[4][4][16];      // [gate][bi][o_local]
    const int tid = threadIdx.x;
    const int otile = blockIdx.x;
    const int qb = blockIdx.y * 4;

    for (int idx = tid; idx < 4 * 768; idx += 256) {
        int bi = idx / 768, k = idx - bi * 768;
        int b = qb + bi;
        float v;
        if (k < 512)      v = y1[b * EE + k];
        else if (k < 640) v = c1[b * OO + (k - 512)];
        else              v = sh1[b * OO + (k - 640)];
        xs[bi][k] = v;
    }
    __syncthreads();

    const int g = tid >> 6, l = tid & 63;   // wave g = gate g
    #pragma unroll 2
    for (int i = 0; i < 16; ++i) {
        const int row = g * 128 + otile * 16 + i;
        const float* wr = Wih + (size_t)row * XDIM;
        float a0 = 0.f, a1 = 0.f, a2 = 0.f, a3 = 0.f;
        #pragma unroll
        for (int j = 0; j < 10; ++j) {
            float wv = wr[l + 64 * j];
            a0 += wv * xs[0][l + 64 * j];
            a1 += wv * xs[1][l + 64 * j];
            a2 += wv * xs[2][l + 64 * j];
            a3 += wv * xs[3][l + 64 * j];
        }
        const float* wh = Whh + (size_t)row * OO;
        #pragma unroll
        for (int j = 0; j < 2; ++j) {
            float wv = wh[l + 64 * j];
            a0 += wv * xs[0][640 + l + 64 * j];
            a1 += wv * xs[1][640 + l + 64 * j];
            a2 += wv * xs[2][640 + l + 64 * j];
            a3 += wv * xs[3][640 + l + 64 * j];
        }
        #pragma unroll
        for (int off = 32; off >= 1; off >>= 1) {
            a0 += __shfl_xor(a0, off);
            a1 += __shfl_xor(a1, off);
            a2 += __shfl_xor(a2, off);
            a3 += __shfl_xor(a3, off);
        }
        if (l == 0) {
            float bb = bih[row] + bhh[row];
            gbuf[g][0][i] = a0 + bb;
            gbuf[g][1][i] = a1 + bb;
            gbuf[g][2][i] = a2 + bb;
            gbuf[g][3][i] = a3 + bb;
        }
    }
    __syncthreads();

    if (tid < 64) {
        const int bi = tid >> 4, ol = tid & 15;
        const int b = qb + bi, o = otile * 16 + ol;
        float gi = gbuf[0][bi][ol], gf = gbuf[1][bi][ol];
        float gg = gbuf[2][bi][ol], go = gbuf[3][bi][ol];
        float sc = sigmoidf_(gf) * sc1[b * OO + o] + sigmoidf_(gi) * tanhf(gg);
        float sh = sigmoidf_(go) * tanhf(sc);
        out_sc[b * OO + o] = sc;
        out_sh[b * OO + o] = sh;
    }
}

// ---------------- K2: raw scores, pure stream.
// 32 lanes own a full 512B row (1 float4/lane): every load instruction is a
// contiguous 1KB wave-segment. No mask, no LDS, no barriers, unconditional loads.
// Wave w handles rows [chunk*128 + w*32, +32) as 16 row-pairs in 2 batches of 8.
__global__ __launch_bounds__(256) void scores_kernel(
    const float* __restrict__ hk, const float* __restrict__ sc,
    float* __restrict__ wbuf)
{
    const int b = blockIdx.y, chunk = blockIdx.x;
    const int tid = threadIdx.x;
    const int w = tid >> 6, lane = tid & 63;
    const int h = lane >> 5, l5 = lane & 31;   // half-wave h owns odd/even rows

    const float4 scv = *(const float4*)(sc + b * OO + l5 * 4);
    const int rbase = chunk * CHUNK_LEN + w * 32;
    const float* kbase = hk + ((size_t)b * TT + rbase) * OO + l5 * 4;
    float* wrow = wbuf + (size_t)b * TT + rbase;

    #pragma unroll
    for (int batch = 0; batch < 2; ++batch) {
        float4 kv[8];
        #pragma unroll
        for (int i = 0; i < 8; ++i)
            kv[i] = *(const float4*)(kbase + (size_t)(batch * 16 + 2 * i + h) * OO);
        #pragma unroll
        for (int i = 0; i < 8; ++i) {
            float p = kv[i].x * scv.x + kv[i].y * scv.y
                    + kv[i].z * scv.z + kv[i].w * scv.w;
            p += __shfl_xor(p, 1);
            p += __shfl_xor(p, 2);
            p += __shfl_xor(p, 4);
            p += __shfl_xor(p, 8);
            p += __shfl_xor(p, 16);
            if (l5 == 0) wrow[batch * 16 + 2 * i + h] = p;
        }
    }
}

// ---------------- K3: per-b masked softmax over scores, in-place -> final weights.
__global__ __launch_bounds__(256) void softmax_kernel(
    float* __restrict__ wbuf, const float* __restrict__ mask)
{
    const int b = blockIdx.x, tid = threadIdx.x;
    const int lane = tid & 63, wv = tid >> 6;
    float* srow = wbuf + (size_t)b * TT;
    const float* mrow = mask + (size_t)b * TT;

    float sarr[8], earr[8];
    bool varr[8];
    float lm = -INFINITY;
    #pragma unroll
    for (int j = 0; j < 8; ++j) {
        int t = tid + 256 * j;
        sarr[j] = srow[t];
        varr[j] = (mrow[t] != 0.f);
        if (varr[j]) lm = fmaxf(lm, sarr[j]);
    }
    #pragma unroll
    for (int off = 32; off >= 1; off >>= 1) lm = fmaxf(lm, __shfl_xor(lm, off));
    __shared__ float red[4];
    if (lane == 0) red[wv] = lm;
    __syncthreads();
    const float M = fmaxf(fmaxf(red[0], red[1]), fmaxf(red[2], red[3]));

    float ls = 0.f;
    #pragma unroll
    for (int j = 0; j < 8; ++j) {
        earr[j] = varr[j] ? __expf(sarr[j] - M) : 0.f;
        ls += earr[j];
    }
    #pragma unroll
    for (int off = 32; off >= 1; off >>= 1) ls += __shfl_xor(ls, off);
    __syncthreads();
    if (lane == 0) red[wv] = ls;
    __syncthreads();
    const float inv = 1.f / (red[0] + red[1] + red[2] + red[3]);
    #pragma unroll
    for (int j = 0; j < 8; ++j) srow[tid + 256 * j] = earr[j] * inv;
}

// ---------------- K4: weighted hv sum, pure stream, normalized weights.
// Same row-ownership as scores. Unconditional loads; w=0 rows contribute 0.
__global__ __launch_bounds__(256) void wsum_kernel(
    const float* __restrict__ hv, const float* __restrict__ wbuf,
    float* __restrict__ ws_c)
{
    const int b = blockIdx.y, chunk = blockIdx.x;
    const int tid = threadIdx.x;
    const int w = tid >> 6, lane = tid & 63;
    const int h = lane >> 5, l5 = lane & 31;

    const int rbase = chunk * CHUNK_LEN + w * 32;
    const float* vbase = hv + ((size_t)b * TT + rbase) * OO + l5 * 4;
    const float* wrow = wbuf + (size_t)b * TT + rbase;

    float4 acc = make_float4(0.f, 0.f, 0.f, 0.f);
    #pragma unroll
    for (int batch = 0; batch < 2; ++batch) {
        float4 vv[8];
        float wr[8];
        #pragma unroll
        for (int i = 0; i < 8; ++i) {
            const int r = batch * 16 + 2 * i + h;
            vv[i] = *(const float4*)(vbase + (size_t)r * OO);
            wr[i] = wrow[r];   // uniform per half-wave: broadcast from L2
        }
        #pragma unroll
        for (int i = 0; i < 8; ++i) {
            acc.x += wr[i] * vv[i].x;
            acc.y += wr[i] * vv[i].y;
            acc.z += wr[i] * vv[i].z;
            acc.w += wr[i] * vv[i].w;
        }
    }
    // add the two half-waves' accumulators (rows interleaved, same o-quad)
    acc.x += __shfl_xor(acc.x, 32);
    acc.y += __shfl_xor(acc.y, 32);
    acc.z += __shfl_xor(acc.z, 32);
    acc.w += __shfl_xor(acc.w, 32);

    __shared__ float pacc[4][128];
    if (h == 0) *(float4*)&pacc[w][l5 * 4] = acc;
    __syncthreads();

    if (tid < 128) {
        float s = pacc[0][tid] + pacc[1][tid] + pacc[2][tid] + pacc[3][tid];
        ws_c[((size_t)b * CHUNKS + chunk) * OO + tid] = s;   // normalized partial
    }
}

// ---------------- K5: combine chunk partials -> c, then MLP head + softmax.
__global__ __launch_bounds__(256) void final_kernel(
    const float* __restrict__ ws_c, const float* __restrict__ sh_in,
    const float* __restrict__ W1, const float* __restrict__ b1,
    const float* __restrict__ W2, const float* __restrict__ b2,
    const float* __restrict__ W3, const float* __restrict__ b3,
    float* __restrict__ out_p, float* __restrict__ out_c)
{
    const int b = blockIdx.x, tid = threadIdx.x;
    __shared__ float cbuf[128], shbuf[128], h1[LL], zz[LL], red2[2];

    if (tid < 128) {
        float s = 0.f;
        const float* base = ws_c + (size_t)b * CHUNKS * OO + tid;
        #pragma unroll
        for (int i = 0; i < CHUNKS; ++i) s += base[i * OO];
        cbuf[tid] = s;
        out_c[b * OO + tid] = s;
        shbuf[tid] = sh_in[b * OO + tid];
    }
    __syncthreads();

    const int o = tid >> 2, l2 = tid & 3;
    if (o < LL) {
        float a = 0.f;
        const float* w1r = W1 + o * OO;
        const float* w2r = W2 + o * OO;
        #pragma unroll 8
        for (int j = 0; j < 32; ++j) {
            int k = l2 + 4 * j;
            a += w1r[k] * shbuf[k] + w2r[k] * cbuf[k];
        }
        a += __shfl_xor(a, 1);
        a += __shfl_xor(a, 2);
        if (l2 == 0) h1[o] = fmaxf(a + b1[o] + b2[o], 0.f);
    }
    __syncthreads();

    if (o < LL) {
        float z = 0.f;
        const float* w3r = W3 + o * LL;
        for (int j = 0; j < 9; ++j) {
            int k = l2 + 4 * j;
            if (k < LL) z += w3r[k] * h1[k];
        }
        z += __shfl_xor(z, 1);
        z += __shfl_xor(z, 2);
        if (l2 == 0) zz[o] = z + b3[o];
    }
    __syncthreads();
    if (tid == 0) {
        float mm = zz[0];
        for (int i = 1; i < LL; i++) mm = fmaxf(mm, zz[i]);
        float ss = 0.f;
        for (int i = 0; i < LL; i++) ss += __expf(zz[i] - mm);
        red2[0] = mm; red2[1] = ss;
    }
    __syncthreads();
    if (tid < LL) out_p[b * LL + tid] = __expf(zz[tid] - red2[0]) / red2[1];
}

extern "C" void kernel_launch(void* const* d_in, const int* in_sizes, int n_in,
                              void* d_out, int out_size, void* d_ws, size_t ws_size,
                              hipStream_t stream) {
    (void)in_sizes; (void)n_in; (void)out_size; (void)ws_size;
    const float* hk   = (const float*)d_in[0];
    const float* hv   = (const float*)d_in[1];
    const float* y1   = (const float*)d_in[2];
    const float* c1   = (const float*)d_in[3];
    const float* sh1  = (const float*)d_in[4];
    const float* sc1  = (const float*)d_in[5];
    const float* mask = (const float*)d_in[6];
    const float* Wih  = (const float*)d_in[7];
    const float* bih  = (const float*)d_in[8];
    const float* Whh  = (const float*)d_in[9];
    const float* bhh  = (const float*)d_in[10];
    const float* W1   = (const float*)d_in[11];
    const float* b1   = (const float*)d_in[12];
    const float* W2   = (const float*)d_in[13];
    const float* b2   = (const float*)d_in[14];
    const float* W3   = (const float*)d_in[15];
    const float* b3   = (const float*)d_in[16];

    float* out    = (float*)d_out;        // [B, L]
    float* out_c  = out + BB * LL;        // [B, O]
    float* out_sh = out_c + BB * OO;      // [B, O]
    float* out_sc = out_sh + BB * OO;     // [B, O]

    float* wbuf = (float*)d_ws;                    // [B, T] scores -> weights (1 MB)
    float* ws_c = wbuf + (size_t)BB * TT;          // [B, CHUNKS, O] partials (1 MB)

    lstm_kernel<<<dim3(8, 32), 256, 0, stream>>>(y1, c1, sh1, sc1, Wih, bih, Whh, bhh,
                                                 out_sh, out_sc);
    scores_kernel<<<dim3(CHUNKS, BB), 256, 0, stream>>>(hk, out_sc, wbuf);
    softmax_kernel<<<BB, 256, 0, stream>>>(wbuf, mask);
    wsum_kernel<<<dim3(CHUNKS, BB), 256, 0, stream>>>(hv, wbuf, ws_c);
    final_kernel<<<BB, 256, 0, stream>>>(ws_c, out_sh, W1, b1, W2, b2, W3, b3,
                                         out, out_c);
}